// Round 1
// baseline (572.873 us; speedup 1.0000x reference)
//
#include <hip/hip_runtime.h>
#include <stdint.h>

#define T_  2048
#define H_  1024
#define NH_ 16
#define HD_ 64

typedef __bf16 bf16x8 __attribute__((ext_vector_type(8)));
typedef float  f32x4  __attribute__((ext_vector_type(4)));

__device__ __forceinline__ unsigned short f2bf(float f) {
  unsigned u = __builtin_bit_cast(unsigned, f);
  u += 0x7fffu + ((u >> 16) & 1u);          // RNE
  return (unsigned short)(u >> 16);
}

union BFrag { unsigned short us[8]; bf16x8 v; };

// ---------------- W_eff = W + 2.0 * B@A  (LoRA fold), store bf16 ----------------
__global__ void prep_weights(const float* __restrict__ Wq, const float* __restrict__ Aq, const float* __restrict__ Bq,
                             const float* __restrict__ Wk, const float* __restrict__ Ak, const float* __restrict__ Bk,
                             const float* __restrict__ Wv, const float* __restrict__ Av, const float* __restrict__ Bv,
                             unsigned short* __restrict__ Weff) {
  int p = blockIdx.y;
  const float* W = (p == 0) ? Wq : (p == 1) ? Wk : Wv;
  const float* A = (p == 0) ? Aq : (p == 1) ? Ak : Av;
  const float* B = (p == 0) ? Bq : (p == 1) ? Bk : Bv;
  int idx = blockIdx.x * 256 + threadIdx.x;      // 0 .. 1M-1
  int o = idx >> 10, h = idx & 1023;
  float acc = W[idx];
#pragma unroll
  for (int r = 0; r < 8; ++r)
    acc += 2.0f * B[o * 8 + r] * A[r * H_ + h];  // SCALING = 16/8 = 2
  Weff[p * (H_ * H_) + idx] = f2bf(acc);
}

// ---------------- x fp32 -> bf16 ----------------
__global__ void convert_x(const float* __restrict__ x, unsigned short* __restrict__ Xb) {
  int i = (blockIdx.x * 256 + threadIdx.x) * 8;
  f32x4 a = *(const f32x4*)(x + i);
  f32x4 c = *(const f32x4*)(x + i + 4);
  uint4 rv;
  rv.x = (unsigned)f2bf(a[0]) | ((unsigned)f2bf(a[1]) << 16);
  rv.y = (unsigned)f2bf(a[2]) | ((unsigned)f2bf(a[3]) << 16);
  rv.z = (unsigned)f2bf(c[0]) | ((unsigned)f2bf(c[1]) << 16);
  rv.w = (unsigned)f2bf(c[2]) | ((unsigned)f2bf(c[3]) << 16);
  *(uint4*)(Xb + i) = rv;
}

// ---------------- QKV GEMM: C[m,n] = sum_k Xb[m,k] * Weff[n,k] (+bias) ----------------
// M=8192, N=3072 (q|k|v), K=1024. 128x128 tile, BK=32, 4 waves, global_load_lds(16B).
#define BM 128
#define BN 128
#define BK 32
__global__ __launch_bounds__(256) void gemm_qkv(
    const unsigned short* __restrict__ Xb, const unsigned short* __restrict__ Weff,
    const float* __restrict__ bq, const float* __restrict__ bk, const float* __restrict__ bv,
    unsigned short* __restrict__ qq, unsigned short* __restrict__ kk, unsigned short* __restrict__ vT) {
  __shared__ __align__(16) unsigned short As[BM][BK];
  __shared__ __align__(16) unsigned short Bs[BN][BK];
  int tid = threadIdx.x;
  int m0 = blockIdx.y * BM;
  int n0 = blockIdx.x * BN;
  int w = tid >> 6, l = tid & 63;
  int wm = w >> 1, wn = w & 1;
  int lr = l & 15, lg = l >> 4;

  f32x4 acc[4][4] = {};
  for (int kt = 0; kt < H_ / BK; ++kt) {
    __syncthreads();
#pragma unroll
    for (int i = 0; i < 2; ++i) {
      int c = tid + i * 256;                     // 512 16B chunks per tile
      int row = c >> 2, ks = (c & 3) * 8;
      const unsigned short* ga = Xb + (size_t)(m0 + row) * H_ + kt * BK + ks;
      const unsigned short* gb = Weff + (size_t)(n0 + row) * H_ + kt * BK + ks;
      __builtin_amdgcn_global_load_lds((const __attribute__((address_space(1))) void*)ga,
                                       (__attribute__((address_space(3))) void*)(&As[0][0] + c * 8), 16, 0, 0);
      __builtin_amdgcn_global_load_lds((const __attribute__((address_space(1))) void*)gb,
                                       (__attribute__((address_space(3))) void*)(&Bs[0][0] + c * 8), 16, 0, 0);
    }
    __syncthreads();                              // compiler drains vmcnt before barrier
    bf16x8 af[4], bf[4];
#pragma unroll
    for (int f = 0; f < 4; ++f) {
      af[f] = *(const bf16x8*)&As[wm * 64 + f * 16 + lr][lg * 8];
      bf[f] = *(const bf16x8*)&Bs[wn * 64 + f * 16 + lr][lg * 8];
    }
#pragma unroll
    for (int fm = 0; fm < 4; ++fm)
#pragma unroll
      for (int fn = 0; fn < 4; ++fn)
        acc[fm][fn] = __builtin_amdgcn_mfma_f32_16x16x32_bf16(af[fm], bf[fn], acc[fm][fn], 0, 0, 0);
  }

  // epilogue: scatter to q[b,h,t,d], k[b,h,t,d], vT[b,h,d,t]  (C/D: col=lane&15, row=(lane>>4)*4+r)
  int p = n0 >> 10;
  const float* bias = (p == 0) ? bq : (p == 1) ? bk : bv;
#pragma unroll
  for (int fm = 0; fm < 4; ++fm) {
    int mbase = m0 + wm * 64 + fm * 16 + lg * 4;
#pragma unroll
    for (int fn = 0; fn < 4; ++fn) {
      int o = (n0 & 1023) + wn * 64 + fn * 16 + lr;
      int hh = o >> 6, d = o & 63;
      float bv_ = bias[o];
#pragma unroll
      for (int r = 0; r < 4; ++r) {
        int m = mbase + r;
        int bb = m >> 11, t = m & 2047;
        unsigned short val = f2bf(acc[fm][fn][r] + bv_);
        size_t bh = (size_t)(bb * NH_ + hh);
        if (p == 0)      qq[(bh * T_ + t) * HD_ + d] = val;
        else if (p == 1) kk[(bh * T_ + t) * HD_ + d] = val;
        else             vT[(bh * HD_ + d) * T_ + t] = val;
      }
    }
  }
}

// ---------------- causal flash attention ----------------
// 1 wave per 16-row Q-tile. S^T = mfma(K,Q) -> lane owns q=lane&15 (8 scores/32-key tile).
// O^T accumulated via mfma(vT, P): lane owns O[q=lane&15][4 d per frag]. All softmax state lane-local.
__global__ __launch_bounds__(256) void attn_fwd(
    const unsigned short* __restrict__ qq, const unsigned short* __restrict__ kk,
    const unsigned short* __restrict__ vT, const float* __restrict__ mask,
    float* __restrict__ out) {
  int w = threadIdx.x >> 6, l = threadIdx.x & 63;
  int task = blockIdx.x * 4 + w;                 // 4*16*128 = 8192 tasks
  int qt = task & 127;
  int bh = task >> 7;
  int b = bh >> 4, h = bh & 15;
  int t0 = qt * 16;
  int lr = l & 15, g = l >> 4;
  int qrow = t0 + lr;

  const unsigned short* Qp = qq + ((size_t)bh * T_ + t0) * HD_;
  const unsigned short* Kp = kk + (size_t)bh * T_ * HD_;
  const unsigned short* Vp = vT + (size_t)bh * HD_ * T_;
  const float* mp = mask + b * T_;

  bf16x8 qf[2];
#pragma unroll
  for (int hs = 0; hs < 2; ++hs)
    qf[hs] = *(const bf16x8*)(Qp + lr * HD_ + hs * 32 + g * 8);

  f32x4 accO[4] = {};
  float m_run = -__builtin_inff(), l_run = 0.f;
  const float L2E = 1.4426950408889634f;
  int kmax = t0 + 16;

  for (int k0 = 0; k0 < kmax; k0 += 32) {
    // S^T: contraction over d (two 32-wide slices)
    f32x4 s0 = {}, s1 = {};
#pragma unroll
    for (int hs = 0; hs < 2; ++hs) {
      bf16x8 kf0 = *(const bf16x8*)(Kp + (size_t)(k0 + lr) * HD_ + hs * 32 + g * 8);
      bf16x8 kf1 = *(const bf16x8*)(Kp + (size_t)(k0 + 16 + lr) * HD_ + hs * 32 + g * 8);
      s0 = __builtin_amdgcn_mfma_f32_16x16x32_bf16(kf0, qf[hs], s0, 0, 0, 0);
      s1 = __builtin_amdgcn_mfma_f32_16x16x32_bf16(kf1, qf[hs], s1, 0, 0, 0);
    }
    f32x4 mv0 = *(const f32x4*)(mp + k0 + g * 4);
    f32x4 mv1 = *(const f32x4*)(mp + k0 + 16 + g * 4);
    float sc0[4], sc1[4];
#pragma unroll
    for (int r = 0; r < 4; ++r) {
      int k_0 = k0 + g * 4 + r, k_1 = k_0 + 16;
      sc0[r] = (k_0 <= qrow) ? s0[r] * 0.125f + mv0[r] : -__builtin_inff();
      sc1[r] = (k_1 <= qrow) ? s1[r] * 0.125f + mv1[r] : -__builtin_inff();
    }
    float pm = fmaxf(fmaxf(fmaxf(sc0[0], sc0[1]), fmaxf(sc0[2], sc0[3])),
                     fmaxf(fmaxf(sc1[0], sc1[1]), fmaxf(sc1[2], sc1[3])));
    pm = fmaxf(pm, __shfl_xor(pm, 16));
    pm = fmaxf(pm, __shfl_xor(pm, 32));
    float m_new = fmaxf(m_run, pm);
    float alpha = exp2f((m_run - m_new) * L2E);
    float p0[4], p1[4], rs = 0.f;
#pragma unroll
    for (int r = 0; r < 4; ++r) {
      p0[r] = exp2f((sc0[r] - m_new) * L2E);
      p1[r] = exp2f((sc1[r] - m_new) * L2E);
      rs += p0[r] + p1[r];
    }
    rs += __shfl_xor(rs, 16);
    rs += __shfl_xor(rs, 32);
    l_run = l_run * alpha + rs;
    m_run = m_new;
#pragma unroll
    for (int dn = 0; dn < 4; ++dn)
#pragma unroll
      for (int r = 0; r < 4; ++r) accO[dn][r] *= alpha;

    // relayout P (C-layout) -> A/B fragment slots: lane l slot j <-> k-local 8*(l>>4)+j
    BFrag pf;
    int srcBase = lr + ((g & 1) ? 32 : 0);
#pragma unroll
    for (int jh = 0; jh < 2; ++jh) {
#pragma unroll
      for (int r = 0; r < 4; ++r) {
        float v0 = __shfl(p0[r], srcBase + jh * 16);
        float v1 = __shfl(p1[r], srcBase + jh * 16);
        pf.us[jh * 4 + r] = f2bf((g >> 1) ? v1 : v0);
      }
    }
    // O^T += Vt * P^T   (contraction over 32 keys)
#pragma unroll
    for (int dn = 0; dn < 4; ++dn) {
      bf16x8 vf = *(const bf16x8*)(Vp + (size_t)(dn * 16 + lr) * T_ + k0 + g * 8);
      accO[dn] = __builtin_amdgcn_mfma_f32_16x16x32_bf16(vf, pf.v, accO[dn], 0, 0, 0);
    }
  }

  float inv = 1.0f / l_run;
  float* op = out + ((size_t)b * T_ + qrow) * H_ + h * HD_;
#pragma unroll
  for (int dn = 0; dn < 4; ++dn)
#pragma unroll
    for (int r = 0; r < 4; ++r)
      op[dn * 16 + g * 4 + r] = accO[dn][r] * inv;
}

extern "C" void kernel_launch(void* const* d_in, const int* in_sizes, int n_in,
                              void* d_out, int out_size, void* d_ws, size_t ws_size,
                              hipStream_t stream) {
  const float* x    = (const float*)d_in[0];
  const float* mask = (const float*)d_in[1];
  const float* Wq = (const float*)d_in[2];
  const float* bq = (const float*)d_in[3];
  const float* Aq = (const float*)d_in[4];
  const float* Bq = (const float*)d_in[5];
  const float* Wk = (const float*)d_in[6];
  const float* bk = (const float*)d_in[7];
  const float* Ak = (const float*)d_in[8];
  const float* Bk = (const float*)d_in[9];
  const float* Wv = (const float*)d_in[10];
  const float* bv = (const float*)d_in[11];
  const float* Av = (const float*)d_in[12];
  const float* Bv = (const float*)d_in[13];
  float* out = (float*)d_out;

  char* ws = (char*)d_ws;
  unsigned short* Xb   = (unsigned short*)(ws);                   // 16 MB  [8192][1024]
  unsigned short* Weff = (unsigned short*)(ws + (16u << 20));     //  6 MB  [3][1024][1024]
  unsigned short* qq   = (unsigned short*)(ws + (22u << 20));     // 16 MB  [4][16][2048][64]
  unsigned short* kk   = (unsigned short*)(ws + (38u << 20));     // 16 MB  [4][16][2048][64]
  unsigned short* vT   = (unsigned short*)(ws + (54u << 20));     // 16 MB  [4][16][64][2048]

  prep_weights<<<dim3(4096, 3), 256, 0, stream>>>(Wq, Aq, Bq, Wk, Ak, Bk, Wv, Av, Bv, Weff);
  convert_x<<<4096, 256, 0, stream>>>(x, Xb);
  gemm_qkv<<<dim3(24, 64), 256, 0, stream>>>(Xb, Weff, bq, bk, bv, qq, kk, vT);
  attn_fwd<<<2048, 256, 0, stream>>>(qq, kk, vT, mask, out);
}

// Round 2
// 446.549 us; speedup vs baseline: 1.2829x; 1.2829x over previous
//
#include <hip/hip_runtime.h>
#include <stdint.h>

#define T_  2048
#define H_  1024
#define NH_ 16
#define HD_ 64

typedef __bf16 bf16x8 __attribute__((ext_vector_type(8)));
typedef __bf16 bf16x4 __attribute__((ext_vector_type(4)));
typedef float  f32x4  __attribute__((ext_vector_type(4)));

__device__ __forceinline__ unsigned short f2bf(float f) {
  unsigned u = __builtin_bit_cast(unsigned, f);
  u += 0x7fffu + ((u >> 16) & 1u);          // RNE
  return (unsigned short)(u >> 16);
}

union BFrag { unsigned short us[8]; bf16x8 v; };

// ---------------- W_eff = W + 2.0 * B@A  (LoRA fold), store bf16 ----------------
__global__ void prep_weights(const float* __restrict__ Wq, const float* __restrict__ Aq, const float* __restrict__ Bq,
                             const float* __restrict__ Wk, const float* __restrict__ Ak, const float* __restrict__ Bk,
                             const float* __restrict__ Wv, const float* __restrict__ Av, const float* __restrict__ Bv,
                             unsigned short* __restrict__ Weff) {
  int p = blockIdx.y;
  const float* W = (p == 0) ? Wq : (p == 1) ? Wk : Wv;
  const float* A = (p == 0) ? Aq : (p == 1) ? Ak : Av;
  const float* B = (p == 0) ? Bq : (p == 1) ? Bk : Bv;
  int idx = blockIdx.x * 256 + threadIdx.x;      // 0 .. 1M-1
  int o = idx >> 10, h = idx & 1023;
  float acc = W[idx];
#pragma unroll
  for (int r = 0; r < 8; ++r)
    acc += 2.0f * B[o * 8 + r] * A[r * H_ + h];  // SCALING = 16/8 = 2
  Weff[p * (H_ * H_) + idx] = f2bf(acc);
}

// ---------------- x fp32 -> bf16 ----------------
__global__ void convert_x(const float* __restrict__ x, unsigned short* __restrict__ Xb) {
  int i = (blockIdx.x * 256 + threadIdx.x) * 8;
  f32x4 a = *(const f32x4*)(x + i);
  f32x4 c = *(const f32x4*)(x + i + 4);
  uint4 rv;
  rv.x = (unsigned)f2bf(a[0]) | ((unsigned)f2bf(a[1]) << 16);
  rv.y = (unsigned)f2bf(a[2]) | ((unsigned)f2bf(a[3]) << 16);
  rv.z = (unsigned)f2bf(c[0]) | ((unsigned)f2bf(c[1]) << 16);
  rv.w = (unsigned)f2bf(c[2]) | ((unsigned)f2bf(c[3]) << 16);
  *(uint4*)(Xb + i) = rv;
}

// ---------------- QKV GEMM: C[m,n] = sum_k Xb[m,k] * Weff[n,k] (+bias) ----------------
#define BM 128
#define BN 128
#define BK 32
__global__ __launch_bounds__(256) void gemm_qkv(
    const unsigned short* __restrict__ Xb, const unsigned short* __restrict__ Weff,
    const float* __restrict__ bq, const float* __restrict__ bk, const float* __restrict__ bv,
    unsigned short* __restrict__ qq, unsigned short* __restrict__ kk, unsigned short* __restrict__ vT) {
  __shared__ __align__(16) unsigned short As[BM][BK];
  __shared__ __align__(16) unsigned short Bs[BN][BK];
  int tid = threadIdx.x;
  int m0 = blockIdx.y * BM;
  int n0 = blockIdx.x * BN;
  int w = tid >> 6, l = tid & 63;
  int wm = w >> 1, wn = w & 1;
  int lr = l & 15, lg = l >> 4;

  f32x4 acc[4][4] = {};
  for (int kt = 0; kt < H_ / BK; ++kt) {
    __syncthreads();
#pragma unroll
    for (int i = 0; i < 2; ++i) {
      int c = tid + i * 256;                     // 512 16B chunks per tile
      int row = c >> 2, ks = (c & 3) * 8;
      const unsigned short* ga = Xb + (size_t)(m0 + row) * H_ + kt * BK + ks;
      const unsigned short* gb = Weff + (size_t)(n0 + row) * H_ + kt * BK + ks;
      __builtin_amdgcn_global_load_lds((const __attribute__((address_space(1))) void*)ga,
                                       (__attribute__((address_space(3))) void*)(&As[0][0] + c * 8), 16, 0, 0);
      __builtin_amdgcn_global_load_lds((const __attribute__((address_space(1))) void*)gb,
                                       (__attribute__((address_space(3))) void*)(&Bs[0][0] + c * 8), 16, 0, 0);
    }
    __syncthreads();
    bf16x8 af[4], bf[4];
#pragma unroll
    for (int f = 0; f < 4; ++f) {
      af[f] = *(const bf16x8*)&As[wm * 64 + f * 16 + lr][lg * 8];
      bf[f] = *(const bf16x8*)&Bs[wn * 64 + f * 16 + lr][lg * 8];
    }
#pragma unroll
    for (int fm = 0; fm < 4; ++fm)
#pragma unroll
      for (int fn = 0; fn < 4; ++fn)
        acc[fm][fn] = __builtin_amdgcn_mfma_f32_16x16x32_bf16(af[fm], bf[fn], acc[fm][fn], 0, 0, 0);
  }

  int p = n0 >> 10;
  const float* bias = (p == 0) ? bq : (p == 1) ? bk : bv;
#pragma unroll
  for (int fm = 0; fm < 4; ++fm) {
    int mbase = m0 + wm * 64 + fm * 16 + lg * 4;
#pragma unroll
    for (int fn = 0; fn < 4; ++fn) {
      int o = (n0 & 1023) + wn * 64 + fn * 16 + lr;
      int hh = o >> 6, d = o & 63;
      float bv_ = bias[o];
#pragma unroll
      for (int r = 0; r < 4; ++r) {
        int m = mbase + r;
        int bb = m >> 11, t = m & 2047;
        unsigned short val = f2bf(acc[fm][fn][r] + bv_);
        size_t bh = (size_t)(bb * NH_ + hh);
        if (p == 0)      qq[(bh * T_ + t) * HD_ + d] = val;
        else if (p == 1) kk[(bh * T_ + t) * HD_ + d] = val;
        else             vT[(bh * HD_ + d) * T_ + t] = val;
      }
    }
  }
}

// ---------------- causal flash attention ----------------
// 1 wave per 32-row Q-tile (two 16-row fragments sharing K/V/mask loads).
// S^T = mfma(K,Q): lane owns q=lane&15, keys {4g+r, 16+4g+r}. P feeds PV MFMA
// directly (zero shuffles): V A-fragment loaded with the SAME permuted k-map
// (two 8B loads: slots 0-3 <- k0+4g+j, slots 4-7 <- k0+16+4g+j).
__global__ __launch_bounds__(256) void attn_fwd(
    const unsigned short* __restrict__ qq, const unsigned short* __restrict__ kk,
    const unsigned short* __restrict__ vT, const float* __restrict__ mask,
    float* __restrict__ out) {
  int w = threadIdx.x >> 6, l = threadIdx.x & 63;
  int task = blockIdx.x * 4 + w;                 // 64 bh * 64 qtiles = 4096 tasks
  int qt = task & 63;
  int bh = task >> 6;
  int b = bh >> 4, h = bh & 15;
  int t0 = qt * 32;
  int lr = l & 15, g = l >> 4;

  const unsigned short* Qp = qq + ((size_t)bh * T_ + t0) * HD_;
  const unsigned short* Kp = kk + (size_t)bh * T_ * HD_;
  const unsigned short* Vp = vT + (size_t)bh * HD_ * T_;
  const float* mp = mask + b * T_;

  bf16x8 qf[2][2];
#pragma unroll
  for (int u = 0; u < 2; ++u)
#pragma unroll
    for (int hs = 0; hs < 2; ++hs)
      qf[u][hs] = *(const bf16x8*)(Qp + (u * 16 + lr) * HD_ + hs * 32 + g * 8);

  f32x4 accO[2][4] = {};
  float m_run[2] = {-__builtin_inff(), -__builtin_inff()};
  float l_run[2] = {0.f, 0.f};
  const float L2E = 1.4426950408889634f;

  for (int k0 = 0; k0 < t0 + 32; k0 += 32) {
    // K fragments (shared by both q-halves)
    bf16x8 kf0[2], kf1[2];
#pragma unroll
    for (int hs = 0; hs < 2; ++hs) {
      kf0[hs] = *(const bf16x8*)(Kp + (size_t)(k0 + lr) * HD_ + hs * 32 + g * 8);
      kf1[hs] = *(const bf16x8*)(Kp + (size_t)(k0 + 16 + lr) * HD_ + hs * 32 + g * 8);
    }
    f32x4 s0[2] = {{0.f,0.f,0.f,0.f},{0.f,0.f,0.f,0.f}};
    f32x4 s1[2] = {{0.f,0.f,0.f,0.f},{0.f,0.f,0.f,0.f}};
#pragma unroll
    for (int u = 0; u < 2; ++u)
#pragma unroll
      for (int hs = 0; hs < 2; ++hs) {
        s0[u] = __builtin_amdgcn_mfma_f32_16x16x32_bf16(kf0[hs], qf[u][hs], s0[u], 0, 0, 0);
        s1[u] = __builtin_amdgcn_mfma_f32_16x16x32_bf16(kf1[hs], qf[u][hs], s1[u], 0, 0, 0);
      }

    // V fragments, permuted k-map to match P's natural layout (shared by halves)
    bf16x8 vf[4];
#pragma unroll
    for (int dn = 0; dn < 4; ++dn) {
      const unsigned short* vrow = Vp + (size_t)(dn * 16 + lr) * T_ + k0 + 4 * g;
      bf16x4 lo = *(const bf16x4*)(vrow);
      bf16x4 hi = *(const bf16x4*)(vrow + 16);
#pragma unroll
      for (int j = 0; j < 4; ++j) { vf[dn][j] = lo[j]; vf[dn][4 + j] = hi[j]; }
    }

    f32x4 mv0 = *(const f32x4*)(mp + k0 + g * 4);
    f32x4 mv1 = *(const f32x4*)(mp + k0 + 16 + g * 4);

#pragma unroll
    for (int u = 0; u < 2; ++u) {
      int qrow = t0 + u * 16 + lr;
      float sc0[4], sc1[4];
#pragma unroll
      for (int r = 0; r < 4; ++r) {
        int k_0 = k0 + g * 4 + r, k_1 = k_0 + 16;
        sc0[r] = (k_0 <= qrow) ? s0[u][r] * 0.125f + mv0[r] : -__builtin_inff();
        sc1[r] = (k_1 <= qrow) ? s1[u][r] * 0.125f + mv1[r] : -__builtin_inff();
      }
      float pm = fmaxf(fmaxf(fmaxf(sc0[0], sc0[1]), fmaxf(sc0[2], sc0[3])),
                       fmaxf(fmaxf(sc1[0], sc1[1]), fmaxf(sc1[2], sc1[3])));
      pm = fmaxf(pm, __shfl_xor(pm, 16));
      pm = fmaxf(pm, __shfl_xor(pm, 32));
      // defer-max (T13, THR=8): only rescale when the running max grew materially
      if (!__all(pm <= m_run[u] + 8.f)) {
        float m_new = fmaxf(m_run[u], pm);
        float alpha = exp2f((m_run[u] - m_new) * L2E);
        l_run[u] *= alpha;
#pragma unroll
        for (int dn = 0; dn < 4; ++dn)
#pragma unroll
          for (int r = 0; r < 4; ++r) accO[u][dn][r] *= alpha;
        m_run[u] = m_new;
      }
      float p0[4], p1[4], rs = 0.f;
#pragma unroll
      for (int r = 0; r < 4; ++r) {
        p0[r] = exp2f((sc0[r] - m_run[u]) * L2E);
        p1[r] = exp2f((sc1[r] - m_run[u]) * L2E);
        rs += p0[r] + p1[r];
      }
      rs += __shfl_xor(rs, 16);
      rs += __shfl_xor(rs, 32);
      l_run[u] += rs;

      // P -> B-fragment: same lane, natural slot order (zero shuffles)
      BFrag pf;
#pragma unroll
      for (int r = 0; r < 4; ++r) {
        pf.us[r]     = f2bf(p0[r]);
        pf.us[4 + r] = f2bf(p1[r]);
      }
#pragma unroll
      for (int dn = 0; dn < 4; ++dn)
        accO[u][dn] = __builtin_amdgcn_mfma_f32_16x16x32_bf16(vf[dn], pf.v, accO[u][dn], 0, 0, 0);
    }
  }

#pragma unroll
  for (int u = 0; u < 2; ++u) {
    float inv = 1.0f / l_run[u];
    float* op = out + ((size_t)b * T_ + t0 + u * 16 + lr) * H_ + h * HD_;
#pragma unroll
    for (int dn = 0; dn < 4; ++dn) {
      f32x4 ov;
#pragma unroll
      for (int r = 0; r < 4; ++r) ov[r] = accO[u][dn][r] * inv;
      *(f32x4*)(op + dn * 16 + g * 4) = ov;
    }
  }
}

extern "C" void kernel_launch(void* const* d_in, const int* in_sizes, int n_in,
                              void* d_out, int out_size, void* d_ws, size_t ws_size,
                              hipStream_t stream) {
  const float* x    = (const float*)d_in[0];
  const float* mask = (const float*)d_in[1];
  const float* Wq = (const float*)d_in[2];
  const float* bq = (const float*)d_in[3];
  const float* Aq = (const float*)d_in[4];
  const float* Bq = (const float*)d_in[5];
  const float* Wk = (const float*)d_in[6];
  const float* bk = (const float*)d_in[7];
  const float* Ak = (const float*)d_in[8];
  const float* Bk = (const float*)d_in[9];
  const float* Wv = (const float*)d_in[10];
  const float* bv = (const float*)d_in[11];
  const float* Av = (const float*)d_in[12];
  const float* Bv = (const float*)d_in[13];
  float* out = (float*)d_out;

  char* ws = (char*)d_ws;
  unsigned short* Xb   = (unsigned short*)(ws);                   // 16 MB  [8192][1024]
  unsigned short* Weff = (unsigned short*)(ws + (16u << 20));     //  6 MB  [3][1024][1024]
  unsigned short* qq   = (unsigned short*)(ws + (22u << 20));     // 16 MB  [4][16][2048][64]
  unsigned short* kk   = (unsigned short*)(ws + (38u << 20));     // 16 MB  [4][16][2048][64]
  unsigned short* vT   = (unsigned short*)(ws + (54u << 20));     // 16 MB  [4][16][64][2048]

  prep_weights<<<dim3(4096, 3), 256, 0, stream>>>(Wq, Aq, Bq, Wk, Ak, Bk, Wv, Av, Bv, Weff);
  convert_x<<<4096, 256, 0, stream>>>(x, Xb);
  gemm_qkv<<<dim3(24, 64), 256, 0, stream>>>(Xb, Weff, bq, bk, bv, qq, kk, vT);
  attn_fwd<<<1024, 256, 0, stream>>>(qq, kk, vT, mask, out);
}

// Round 3
// 234.162 us; speedup vs baseline: 2.4465x; 1.9070x over previous
//
#include <hip/hip_runtime.h>
#include <stdint.h>

#define T_  2048
#define H_  1024
#define NH_ 16
#define HD_ 64

typedef __bf16 bf16x8 __attribute__((ext_vector_type(8)));
typedef float  f32x4  __attribute__((ext_vector_type(4)));

__device__ __forceinline__ unsigned short f2bf(float f) {
  unsigned u = __builtin_bit_cast(unsigned, f);
  u += 0x7fffu + ((u >> 16) & 1u);          // RNE
  return (unsigned short)(u >> 16);
}

// ---------------- W_eff = W + 2.0 * B@A  (LoRA fold), store bf16 ----------------
__global__ void prep_weights(const float* __restrict__ Wq, const float* __restrict__ Aq, const float* __restrict__ Bq,
                             const float* __restrict__ Wk, const float* __restrict__ Ak, const float* __restrict__ Bk,
                             const float* __restrict__ Wv, const float* __restrict__ Av, const float* __restrict__ Bv,
                             unsigned short* __restrict__ Weff) {
  int p = blockIdx.y;
  const float* W = (p == 0) ? Wq : (p == 1) ? Wk : Wv;
  const float* A = (p == 0) ? Aq : (p == 1) ? Ak : Av;
  const float* B = (p == 0) ? Bq : (p == 1) ? Bk : Bv;
  int idx = blockIdx.x * 256 + threadIdx.x;      // 0 .. 1M-1
  int o = idx >> 10, h = idx & 1023;
  float acc = W[idx];
#pragma unroll
  for (int r = 0; r < 8; ++r)
    acc += 2.0f * B[o * 8 + r] * A[r * H_ + h];  // SCALING = 16/8 = 2
  Weff[p * (H_ * H_) + idx] = f2bf(acc);
}

// ---------------- x fp32 -> bf16 ----------------
__global__ void convert_x(const float* __restrict__ x, unsigned short* __restrict__ Xb) {
  int i = (blockIdx.x * 256 + threadIdx.x) * 8;
  f32x4 a = *(const f32x4*)(x + i);
  f32x4 c = *(const f32x4*)(x + i + 4);
  uint4 rv;
  rv.x = (unsigned)f2bf(a[0]) | ((unsigned)f2bf(a[1]) << 16);
  rv.y = (unsigned)f2bf(a[2]) | ((unsigned)f2bf(a[3]) << 16);
  rv.z = (unsigned)f2bf(c[0]) | ((unsigned)f2bf(c[1]) << 16);
  rv.w = (unsigned)f2bf(c[2]) | ((unsigned)f2bf(c[3]) << 16);
  *(uint4*)(Xb + i) = rv;
}

// ---------------- QKV GEMM: C[m,n] = sum_k Xb[m,k] * Weff[n,k] (+bias) ----------------
// Epilogue: q scaled by 1/8 (softmax scale folded, exact pow2); V stored PRE-PERMUTED
// so attn's PV A-fragment is a single contiguous 16B load (slot map = P's natural map).
#define BM 128
#define BN 128
#define BK 32
__global__ __launch_bounds__(256) void gemm_qkv(
    const unsigned short* __restrict__ Xb, const unsigned short* __restrict__ Weff,
    const float* __restrict__ bq, const float* __restrict__ bk, const float* __restrict__ bv,
    unsigned short* __restrict__ qq, unsigned short* __restrict__ kk, unsigned short* __restrict__ vP) {
  __shared__ __align__(16) unsigned short As[BM][BK];
  __shared__ __align__(16) unsigned short Bs[BN][BK];
  int tid = threadIdx.x;
  int m0 = blockIdx.y * BM;
  int n0 = blockIdx.x * BN;
  int w = tid >> 6, l = tid & 63;
  int wm = w >> 1, wn = w & 1;
  int lr = l & 15, lg = l >> 4;

  f32x4 acc[4][4] = {};
  for (int kt = 0; kt < H_ / BK; ++kt) {
    __syncthreads();
#pragma unroll
    for (int i = 0; i < 2; ++i) {
      int c = tid + i * 256;                     // 512 16B chunks per tile
      int row = c >> 2, ks = (c & 3) * 8;
      const unsigned short* ga = Xb + (size_t)(m0 + row) * H_ + kt * BK + ks;
      const unsigned short* gb = Weff + (size_t)(n0 + row) * H_ + kt * BK + ks;
      __builtin_amdgcn_global_load_lds((const __attribute__((address_space(1))) void*)ga,
                                       (__attribute__((address_space(3))) void*)(&As[0][0] + c * 8), 16, 0, 0);
      __builtin_amdgcn_global_load_lds((const __attribute__((address_space(1))) void*)gb,
                                       (__attribute__((address_space(3))) void*)(&Bs[0][0] + c * 8), 16, 0, 0);
    }
    __syncthreads();
    bf16x8 af[4], bf[4];
#pragma unroll
    for (int f = 0; f < 4; ++f) {
      af[f] = *(const bf16x8*)&As[wm * 64 + f * 16 + lr][lg * 8];
      bf[f] = *(const bf16x8*)&Bs[wn * 64 + f * 16 + lr][lg * 8];
    }
#pragma unroll
    for (int fm = 0; fm < 4; ++fm)
#pragma unroll
      for (int fn = 0; fn < 4; ++fn)
        acc[fm][fn] = __builtin_amdgcn_mfma_f32_16x16x32_bf16(af[fm], bf[fn], acc[fm][fn], 0, 0, 0);
  }

  int p = n0 >> 10;
  const float* bias = (p == 0) ? bq : (p == 1) ? bk : bv;
#pragma unroll
  for (int fm = 0; fm < 4; ++fm) {
    int mbase = m0 + wm * 64 + fm * 16 + lg * 4;
#pragma unroll
    for (int fn = 0; fn < 4; ++fn) {
      int o = (n0 & 1023) + wn * 64 + fn * 16 + lr;
      int hh = o >> 6, d = o & 63;
      float bv_ = bias[o];
#pragma unroll
      for (int r = 0; r < 4; ++r) {
        int m = mbase + r;
        int bb = m >> 11, t = m & 2047;
        float v = acc[fm][fn][r] + bv_;
        size_t bh = (size_t)(bb * NH_ + hh);
        if (p == 0) {
          qq[(bh * T_ + t) * HD_ + d] = f2bf(v * 0.125f);   // fold 1/sqrt(64)
        } else if (p == 1) {
          kk[(bh * T_ + t) * HD_ + d] = f2bf(v);
        } else {
          // permuted position within 32-key tile: slot(g,j,hi) = g*8 + j + hi*4
          int r5 = t & 31;
          int within = ((r5 >> 2) & 3) * 8 + (r5 & 3) + ((r5 >> 4) << 2);
          vP[(bh * HD_ + d) * T_ + (t & ~31) + within] = f2bf(v);
        }
      }
    }
  }
}

// ---------------- causal flash attention ----------------
// 1 wave per Q-tile PAIR (qt, 63-qt): uniform 65 k-tiles/wave -> no tail imbalance.
// Register ping-pong double-buffer for K/V/mask (issue-early, T14).
// S^T = mfma(K,Q); P feeds PV directly (zero shuffles, V pre-permuted).
__global__ __launch_bounds__(256, 2) void attn_fwd(
    const unsigned short* __restrict__ qq, const unsigned short* __restrict__ kk,
    const unsigned short* __restrict__ vP, const float* __restrict__ mask,
    float* __restrict__ out) {
  int w = threadIdx.x >> 6, l = threadIdx.x & 63;
  int wid = blockIdx.x * 4 + w;                  // 2048 waves
  int bh = wid >> 5, pr = wid & 31;
  int b = bh >> 4, h = bh & 15;
  int lr = l & 15, g = l >> 4;
  const float L2E = 1.4426950408889634f;
  const float NINF = -__builtin_inff();

  const unsigned short* Kp = kk + (size_t)bh * T_ * HD_;
  const unsigned short* Vp = vP + (size_t)bh * HD_ * T_;
  const float* mp = mask + b * T_;

#pragma unroll
  for (int s = 0; s < 2; ++s) {
    int qt = s ? (63 - pr) : pr;
    int t0 = qt * 32;
    int nt = qt + 1;
    const unsigned short* Qp = qq + ((size_t)bh * T_ + t0) * HD_;

    bf16x8 qf[2][2];
#pragma unroll
    for (int u = 0; u < 2; ++u)
#pragma unroll
      for (int hs = 0; hs < 2; ++hs)
        qf[u][hs] = *(const bf16x8*)(Qp + (u * 16 + lr) * HD_ + hs * 32 + g * 8);

    f32x4 accO[2][4] = {};
    float m_run[2] = {NINF, NINF};
    float l_run[2] = {0.f, 0.f};

    // double-buffer registers (named, static-indexed)
    bf16x8 kA0[2], kA1[2], vA[4], kB0[2], kB1[2], vB[4];
    f32x4 mA0, mA1, mB0, mB1;

    auto load_tile = [&](int k0, bf16x8 (&kd0)[2], bf16x8 (&kd1)[2], bf16x8 (&vd)[4],
                         f32x4& md0, f32x4& md1) {
#pragma unroll
      for (int hs = 0; hs < 2; ++hs) {
        kd0[hs] = *(const bf16x8*)(Kp + (size_t)(k0 + lr) * HD_ + hs * 32 + g * 8);
        kd1[hs] = *(const bf16x8*)(Kp + (size_t)(k0 + 16 + lr) * HD_ + hs * 32 + g * 8);
      }
#pragma unroll
      for (int dn = 0; dn < 4; ++dn)
        vd[dn] = *(const bf16x8*)(Vp + (size_t)(dn * 16 + lr) * T_ + k0 + g * 8);
      md0 = *(const f32x4*)(mp + k0 + g * 4);
      md1 = *(const f32x4*)(mp + k0 + 16 + g * 4);
    };

    auto step = [&](int ti, bf16x8 (&kc0)[2], bf16x8 (&kc1)[2], bf16x8 (&vc)[4],
                    f32x4& mc0, f32x4& mc1,
                    bf16x8 (&kn0)[2], bf16x8 (&kn1)[2], bf16x8 (&vn)[4],
                    f32x4& mn0, f32x4& mn1) {
      int k0 = ti * 32;
      f32x4 s0[2] = {{0.f,0.f,0.f,0.f},{0.f,0.f,0.f,0.f}};
      f32x4 s1[2] = {{0.f,0.f,0.f,0.f},{0.f,0.f,0.f,0.f}};
#pragma unroll
      for (int u = 0; u < 2; ++u)
#pragma unroll
        for (int hs = 0; hs < 2; ++hs) {
          s0[u] = __builtin_amdgcn_mfma_f32_16x16x32_bf16(kc0[hs], qf[u][hs], s0[u], 0, 0, 0);
          s1[u] = __builtin_amdgcn_mfma_f32_16x16x32_bf16(kc1[hs], qf[u][hs], s1[u], 0, 0, 0);
        }
      // issue next tile's loads early: latency hides under softmax+PV
      int k1 = k0 + 32;
      if (k1 <= t0) load_tile(k1, kn0, kn1, vn, mn0, mn1);

      bool diag = (ti == nt - 1);
#pragma unroll
      for (int u = 0; u < 2; ++u) {
        float sc0[4], sc1[4];
        if (diag) {
          int qrow = t0 + u * 16 + lr;
#pragma unroll
          for (int r = 0; r < 4; ++r) {
            int ka = k0 + g * 4 + r;
            sc0[r] = (ka <= qrow)      ? s0[u][r] + mc0[r] : NINF;
            sc1[r] = (ka + 16 <= qrow) ? s1[u][r] + mc1[r] : NINF;
          }
        } else {
#pragma unroll
          for (int r = 0; r < 4; ++r) {
            sc0[r] = s0[u][r] + mc0[r];
            sc1[r] = s1[u][r] + mc1[r];
          }
        }
        float pm = fmaxf(fmaxf(fmaxf(sc0[0], sc0[1]), fmaxf(sc0[2], sc0[3])),
                         fmaxf(fmaxf(sc1[0], sc1[1]), fmaxf(sc1[2], sc1[3])));
        pm = fmaxf(pm, __shfl_xor(pm, 16));
        pm = fmaxf(pm, __shfl_xor(pm, 32));
        // defer-max (T13, THR=8)
        if (!__all(pm <= m_run[u] + 8.f)) {
          float m_new = fmaxf(m_run[u], pm);
          float alpha = exp2f((m_run[u] - m_new) * L2E);
          l_run[u] *= alpha;
#pragma unroll
          for (int dn = 0; dn < 4; ++dn)
#pragma unroll
            for (int r = 0; r < 4; ++r) accO[u][dn][r] *= alpha;
          m_run[u] = m_new;
        }
        float p0[4], p1[4], rsl = 0.f;
#pragma unroll
        for (int r = 0; r < 4; ++r) {
          p0[r] = exp2f((sc0[r] - m_run[u]) * L2E);
          p1[r] = exp2f((sc1[r] - m_run[u]) * L2E);
          rsl += p0[r] + p1[r];
        }
        l_run[u] += rsl;                          // lane-local partial; reduced once at end
        bf16x8 pv_;
#pragma unroll
        for (int r = 0; r < 4; ++r) {
          pv_[r]     = (__bf16)p0[r];
          pv_[4 + r] = (__bf16)p1[r];
        }
#pragma unroll
        for (int dn = 0; dn < 4; ++dn)
          accO[u][dn] = __builtin_amdgcn_mfma_f32_16x16x32_bf16(vc[dn], pv_, accO[u][dn], 0, 0, 0);
      }
    };

    load_tile(0, kA0, kA1, vA, mA0, mA1);
    int ti = 0;
    for (;;) {
      step(ti, kA0, kA1, vA, mA0, mA1, kB0, kB1, vB, mB0, mB1);
      if (++ti == nt) break;
      step(ti, kB0, kB1, vB, mB0, mB1, kA0, kA1, vA, mA0, mA1);
      if (++ti == nt) break;
    }

#pragma unroll
    for (int u = 0; u < 2; ++u) {
      float lt = l_run[u];
      lt += __shfl_xor(lt, 16);
      lt += __shfl_xor(lt, 32);
      float inv = 1.0f / lt;
      float* op = out + ((size_t)b * T_ + t0 + u * 16 + lr) * H_ + h * HD_;
#pragma unroll
      for (int dn = 0; dn < 4; ++dn) {
        f32x4 ov;
#pragma unroll
        for (int r = 0; r < 4; ++r) ov[r] = accO[u][dn][r] * inv;
        *(f32x4*)(op + dn * 16 + g * 4) = ov;
      }
    }
  }
}

extern "C" void kernel_launch(void* const* d_in, const int* in_sizes, int n_in,
                              void* d_out, int out_size, void* d_ws, size_t ws_size,
                              hipStream_t stream) {
  const float* x    = (const float*)d_in[0];
  const float* mask = (const float*)d_in[1];
  const float* Wq = (const float*)d_in[2];
  const float* bq = (const float*)d_in[3];
  const float* Aq = (const float*)d_in[4];
  const float* Bq = (const float*)d_in[5];
  const float* Wk = (const float*)d_in[6];
  const float* bk = (const float*)d_in[7];
  const float* Ak = (const float*)d_in[8];
  const float* Bk = (const float*)d_in[9];
  const float* Wv = (const float*)d_in[10];
  const float* bv = (const float*)d_in[11];
  const float* Av = (const float*)d_in[12];
  const float* Bv = (const float*)d_in[13];
  float* out = (float*)d_out;

  char* ws = (char*)d_ws;
  unsigned short* Xb   = (unsigned short*)(ws);                   // 16 MB  [8192][1024]
  unsigned short* Weff = (unsigned short*)(ws + (16u << 20));     //  6 MB  [3][1024][1024]
  unsigned short* qq   = (unsigned short*)(ws + (22u << 20));     // 16 MB  [4][16][2048][64]
  unsigned short* kk   = (unsigned short*)(ws + (38u << 20));     // 16 MB  [4][16][2048][64]
  unsigned short* vP   = (unsigned short*)(ws + (54u << 20));     // 16 MB  [4][16][64][2048] (permuted tiles)

  prep_weights<<<dim3(4096, 3), 256, 0, stream>>>(Wq, Aq, Bq, Wk, Ak, Bk, Wv, Av, Bv, Weff);
  convert_x<<<4096, 256, 0, stream>>>(x, Xb);
  gemm_qkv<<<dim3(24, 64), 256, 0, stream>>>(Xb, Weff, bq, bk, bv, qq, kk, vP);
  attn_fwd<<<512, 256, 0, stream>>>(qq, kk, vP, mask, out);
}